// Round 1
// baseline (2878.815 us; speedup 1.0000x reference)
//
#include <hip/hip_runtime.h>

// Problem constants (match reference)
#define Bb   64
#define Cc   32        // channels per block (C and C_OUT)
#define Nn   500       // nodes
#define Ll   12        // sequence length
#define WT   32        // output-node tile per block
#define VK   8         // v-chunk staged in LDS
#define CROW 6000      // Nn*Ll, floats per (b,c) row
#define CSTR 388       // padded c-stride in ts (384+4 -> 4-way not 32-way conflicts)
#define WSTR 33        // padded stride for W tile [c][o]

// LDS carve (floats):
//   [0, 12416)        ts  : mix staging tile, c-stride CSTR (32*388)
//     aliased in phase 1: xs [VK][32][12] = [0,3072), as_ [VK][32] = [3072,3328)
//   [12416, 13472)    Ws  : W slice transposed, Ws[c*33+o]
#define SMEM_FLOATS (12416 + 1056)

// out[b,o,w,l] (+)= sum_c Wblk[o,c] * (sum_v in[b,c,v,l] * A[v,w]);  t_out = hop result
__global__ __launch_bounds__(256, 3) void hopmix_kernel(
    const float* __restrict__ in,    // [B,32,500,12]
    const float* __restrict__ A,     // [500,500] or [B,500,500]
    long a_bstride,                  // 0 (static) or Nn*Nn (batched)
    const float* __restrict__ W,     // [32,288]
    int blk,                         // which 32-col block of W
    float* __restrict__ out,         // [B,32,500,12], accumulated (+=)
    float* __restrict__ t_out)       // nullable: store hop result [B,32,500,12]
{
    __shared__ float smem[SMEM_FLOATS];
    float* ts  = smem;
    float* xs  = smem;          // [VK][32][12]
    float* as_ = smem + 3072;   // [VK][32]
    float* Ws  = smem + 12416;  // [32*33]

    const int t  = threadIdx.x;
    const int b  = blockIdx.y;
    const int w0 = blockIdx.x * WT;
    const int c  = t & 31;      // channel owned in phase 1 / o in phase 2
    const int wq = t >> 5;      // 0..7

    // Load W slice transposed: Ws[c][o] = W[o][blk*32+c]
    #pragma unroll
    for (int k = 0; k < 4; ++k) {
        int idx = t + 256 * k;          // 0..1023
        int o = idx >> 5, cc = idx & 31;
        Ws[cc * WSTR + o] = W[o * 288 + blk * 32 + cc];
    }

    const float* Ab = A + (long)b * a_bstride;
    const float* xb = in + (long)b * (Cc * CROW);

    float acc[4][12];
    #pragma unroll
    for (int j = 0; j < 4; ++j)
        #pragma unroll
        for (int l = 0; l < 12; ++l) acc[j][l] = 0.f;

    for (int v0 = 0; v0 < Nn; v0 += VK) {
        __syncthreads();  // previous chunk's reads complete before overwrite
        // Stage x chunk: per c, 96 contiguous floats (VK v's * 12 l) = 24 float4
        #pragma unroll
        for (int k = 0; k < 3; ++k) {
            int f  = t + 256 * k;       // float4 idx 0..767
            int cc = f / 24;
            int r4 = f % 24;            // float4 within run; float off = r4*4
            int vl = r4 / 3;            // (r4*4)/12
            int lo = (r4 - vl * 3) * 4; // 0,4,8
            float4 val = make_float4(0.f, 0.f, 0.f, 0.f);
            if (v0 + vl < Nn)
                val = *(const float4*)(xb + (long)cc * CROW + (long)v0 * Ll + r4 * 4);
            *(float4*)(xs + vl * 384 + cc * 12 + lo) = val;
        }
        // Stage A chunk: as_[vl][wl] = A[v0+vl][w0+wl]
        {
            int vl = t >> 5, wl = t & 31;
            float a = 0.f;
            if (v0 + vl < Nn && w0 + wl < Nn)
                a = Ab[(long)(v0 + vl) * Nn + (w0 + wl)];
            as_[vl * 32 + wl] = a;
        }
        __syncthreads();
        #pragma unroll
        for (int vl = 0; vl < VK; ++vl) {
            float xv[12];
            #pragma unroll
            for (int q = 0; q < 3; ++q)
                *(float4*)(xv + 4 * q) = *(const float4*)(xs + vl * 384 + c * 12 + 4 * q);
            #pragma unroll
            for (int j = 0; j < 4; ++j) {
                float a = as_[vl * 32 + wq + 8 * j];
                #pragma unroll
                for (int l = 0; l < 12; ++l) acc[j][l] += xv[l] * a;
            }
        }
    }

    __syncthreads();  // all xs reads done; ts aliases xs
    // Registers -> ts[c][w][l] (c-stride CSTR)
    #pragma unroll
    for (int j = 0; j < 4; ++j) {
        int w = wq + 8 * j;
        #pragma unroll
        for (int q = 0; q < 3; ++q)
            *(float4*)(ts + c * CSTR + w * 12 + 4 * q) =
                make_float4(acc[j][4 * q], acc[j][4 * q + 1], acc[j][4 * q + 2], acc[j][4 * q + 3]);
    }
    __syncthreads();

    // Optional coalesced store of the hop result
    if (t_out) {
        #pragma unroll
        for (int k = 0; k < 12; ++k) {
            int f  = t + 256 * k;       // float4 idx 0..3071
            int cc = f / 96;
            int r4 = f % 96;            // float off r4*4 in the 384-float (w,l) run
            if (w0 + r4 / 3 < Nn)
                *(float4*)(t_out + (long)(b * Cc + cc) * CROW + (long)w0 * Ll + r4 * 4) =
                    *(const float4*)(ts + cc * CSTR + r4 * 4);
        }
    }

    // Mix epilogue: thread owns (o=c, w=wq+8j); out += Wblk^T applied over c
    float acc2[4][12];
    #pragma unroll
    for (int j = 0; j < 4; ++j)
        #pragma unroll
        for (int l = 0; l < 12; ++l) acc2[j][l] = 0.f;

    for (int cc = 0; cc < 32; ++cc) {
        float wc = Ws[cc * WSTR + c];
        #pragma unroll
        for (int j = 0; j < 4; ++j) {
            const float4* tp = (const float4*)(ts + cc * CSTR + (wq + 8 * j) * 12);
            #pragma unroll
            for (int q = 0; q < 3; ++q) {
                float4 tv = tp[q];
                acc2[j][4 * q]     += wc * tv.x;
                acc2[j][4 * q + 1] += wc * tv.y;
                acc2[j][4 * q + 2] += wc * tv.z;
                acc2[j][4 * q + 3] += wc * tv.w;
            }
        }
    }
    #pragma unroll
    for (int j = 0; j < 4; ++j) {
        int w = w0 + wq + 8 * j;
        if (w < Nn) {
            float4* op = (float4*)(out + ((long)(b * Cc + c) * Nn + w) * Ll);
            #pragma unroll
            for (int q = 0; q < 3; ++q) {
                float4 v = op[q];
                v.x += acc2[j][4 * q];
                v.y += acc2[j][4 * q + 1];
                v.z += acc2[j][4 * q + 2];
                v.w += acc2[j][4 * q + 3];
                op[q] = v;
            }
        }
    }
}

// out[b,o,w,l] = bias[o] + sum_c W[o,c] * x[b,c,w,l]   (block 0 of W; initializes out)
__global__ __launch_bounds__(256, 3) void mix0_kernel(
    const float* __restrict__ x,
    const float* __restrict__ W,
    const float* __restrict__ bias,
    float* __restrict__ out)
{
    __shared__ float smem[SMEM_FLOATS];
    float* ts = smem;
    float* Ws = smem + 12416;

    const int t  = threadIdx.x;
    const int b  = blockIdx.y;
    const int w0 = blockIdx.x * WT;
    const int o  = t & 31;
    const int wq = t >> 5;

    #pragma unroll
    for (int k = 0; k < 4; ++k) {
        int idx = t + 256 * k;
        int oo = idx >> 5, cc = idx & 31;
        Ws[cc * WSTR + oo] = W[oo * 288 + cc];  // block 0
    }
    // Stage x tile into ts (coalesced)
    #pragma unroll
    for (int k = 0; k < 12; ++k) {
        int f  = t + 256 * k;
        int cc = f / 96;
        int r4 = f % 96;
        float4 val = make_float4(0.f, 0.f, 0.f, 0.f);
        if (w0 + r4 / 3 < Nn)
            val = *(const float4*)(x + (long)(b * Cc + cc) * CROW + (long)w0 * Ll + r4 * 4);
        *(float4*)(ts + cc * CSTR + r4 * 4) = val;
    }
    __syncthreads();

    float acc2[4][12];
    #pragma unroll
    for (int j = 0; j < 4; ++j)
        #pragma unroll
        for (int l = 0; l < 12; ++l) acc2[j][l] = 0.f;

    for (int cc = 0; cc < 32; ++cc) {
        float wc = Ws[cc * WSTR + o];
        #pragma unroll
        for (int j = 0; j < 4; ++j) {
            const float4* tp = (const float4*)(ts + cc * CSTR + (wq + 8 * j) * 12);
            #pragma unroll
            for (int q = 0; q < 3; ++q) {
                float4 tv = tp[q];
                acc2[j][4 * q]     += wc * tv.x;
                acc2[j][4 * q + 1] += wc * tv.y;
                acc2[j][4 * q + 2] += wc * tv.z;
                acc2[j][4 * q + 3] += wc * tv.w;
            }
        }
    }
    float bo = bias[o];
    #pragma unroll
    for (int j = 0; j < 4; ++j) {
        int w = w0 + wq + 8 * j;
        if (w < Nn) {
            float4* op = (float4*)(out + ((long)(b * Cc + o) * Nn + w) * Ll);
            #pragma unroll
            for (int q = 0; q < 3; ++q) {
                float4 v;
                v.x = bo + acc2[j][4 * q];
                v.y = bo + acc2[j][4 * q + 1];
                v.z = bo + acc2[j][4 * q + 2];
                v.w = bo + acc2[j][4 * q + 3];
                op[q] = v;
            }
        }
    }
}

extern "C" void kernel_launch(void* const* d_in, const int* in_sizes, int n_in,
                              void* d_out, int out_size, void* d_ws, size_t ws_size,
                              hipStream_t stream) {
    const float* x    = (const float*)d_in[0];
    const float* A0   = (const float*)d_in[1];
    const float* A1   = (const float*)d_in[2];
    const float* A2   = (const float*)d_in[3];
    const float* A3   = (const float*)d_in[4];
    const float* W    = (const float*)d_in[5];
    const float* bias = (const float*)d_in[6];
    float* out = (float*)d_out;
    float* t1  = (float*)d_ws;   // [B,32,500,12] scratch = 49.15 MB

    dim3 grid((Nn + WT - 1) / WT, Bb);  // (16, 64)
    dim3 block(256);
    const long BS = (long)Nn * Nn;

    mix0_kernel<<<grid, block, 0, stream>>>(x, W, bias, out);
    // A0
    hopmix_kernel<<<grid, block, 0, stream>>>(x,  A0, 0, W, 1, out, t1);
    hopmix_kernel<<<grid, block, 0, stream>>>(t1, A0, 0, W, 2, out, nullptr);
    // A1
    hopmix_kernel<<<grid, block, 0, stream>>>(x,  A1, 0, W, 3, out, t1);
    hopmix_kernel<<<grid, block, 0, stream>>>(t1, A1, 0, W, 4, out, nullptr);
    // A2
    hopmix_kernel<<<grid, block, 0, stream>>>(x,  A2, 0, W, 5, out, t1);
    hopmix_kernel<<<grid, block, 0, stream>>>(t1, A2, 0, W, 6, out, nullptr);
    // A3 (batched adjacency)
    hopmix_kernel<<<grid, block, 0, stream>>>(x,  A3, BS, W, 7, out, t1);
    hopmix_kernel<<<grid, block, 0, stream>>>(t1, A3, BS, W, 8, out, nullptr);
}

// Round 2
// 1163.030 us; speedup vs baseline: 2.4753x; 2.4753x over previous
//
#include <hip/hip_runtime.h>

typedef unsigned short u16;
typedef __bf16 bf16x8 __attribute__((ext_vector_type(8)));
typedef float f32x4 __attribute__((ext_vector_type(4)));

#define NN 500
#define LLc 12
#define CC 32
#define MM 384          // CC*LLc rows per batch
#define KP 512          // padded K
#define MT 96           // M tile (8 channels * 12)
#define NT 256          // N tile
#define XS_S 40         // LDS row stride (bf16) for X tile  (96x40)
#define AS_S 40         // LDS row stride (bf16) for A tile  (256x40)
#define CT_S 264        // LDS row stride (bf16) for C tile  (96x264)
#define TS_S 384        // mix LDS c-stride (floats): 12*32

__device__ __forceinline__ u16 f2bf(float f) {
    union { float f; unsigned u; } cv; cv.f = f;
    unsigned u = cv.u;
    u += 0x7fffu + ((u >> 16) & 1u);    // RNE
    return (u16)(u >> 16);
}
__device__ __forceinline__ float bf2f(u16 s) {
    union { unsigned u; float f; } cv; cv.u = ((unsigned)s) << 16;
    return cv.f;
}

// ---------------- pre-pass: A [nb][500][500] f32 -> At [nb][500][512] bf16 transposed
__global__ __launch_bounds__(256) void atrans_kernel(
    const float* __restrict__ A, long in_bstride,
    u16* __restrict__ At, long out_bstride)
{
    __shared__ u16 Ls[32 * 36];
    const int t = threadIdx.x;
    const int n0 = blockIdx.x * 32;
    const int k0 = blockIdx.y * 32;
    const float* Ab = A + (long)blockIdx.z * in_bstride;
    u16* Ob = At + (long)blockIdx.z * out_bstride;
    {
        int vl = t >> 3, u = t & 7;
        float4 v = make_float4(0.f, 0.f, 0.f, 0.f);
        if (k0 + vl < NN && n0 + 4 * u + 4 <= NN)
            v = *(const float4*)(Ab + (long)(k0 + vl) * NN + n0 + 4 * u);
        int nb = 4 * u;
        Ls[(nb + 0) * 36 + vl] = f2bf(v.x);
        Ls[(nb + 1) * 36 + vl] = f2bf(v.y);
        Ls[(nb + 2) * 36 + vl] = f2bf(v.z);
        Ls[(nb + 3) * 36 + vl] = f2bf(v.w);
    }
    __syncthreads();
    {
        int row = t >> 3, u = t & 7;
        if (n0 + row < NN)
            *(uint2*)(Ob + (long)(n0 + row) * KP + k0 + 4 * u) = *(const uint2*)(&Ls[row * 36 + 4 * u]);
    }
}

// ---------------- pre-pass: x [b][32][500][12] f32 -> Xt [b][384][512] bf16 (k=v contiguous)
__global__ __launch_bounds__(256) void xpose_kernel(
    const float* __restrict__ x, u16* __restrict__ Xt)
{
    __shared__ u16 Ls[MM * 36];
    const int t = threadIdx.x;
    const int v0 = blockIdx.x * 32;
    const int b  = blockIdx.y;
    #pragma unroll
    for (int j = 0; j < 12; ++j) {
        int f = t + 256 * j;        // 0..3071 float4 over 8? no: 32c*96
        int c = f / 96;
        int r = f - c * 96;
        int vl = r / 3;
        int l3 = (r - vl * 3) * 4;
        float4 v = make_float4(0.f, 0.f, 0.f, 0.f);
        if (v0 + vl < NN)
            v = *(const float4*)(x + ((long)b * CC + c) * (NN * LLc) + (long)(v0 + vl) * LLc + l3);
        int mb = (c * LLc + l3) * 36 + vl;
        Ls[mb]       = f2bf(v.x);
        Ls[mb + 36]  = f2bf(v.y);
        Ls[mb + 72]  = f2bf(v.z);
        Ls[mb + 108] = f2bf(v.w);
    }
    __syncthreads();
    #pragma unroll
    for (int j = 0; j < 12; ++j) {
        int f = t + 256 * j;        // 0..3071 uint2: 384 rows x 8
        int row = f >> 3, u = f & 7;
        *(uint2*)(Xt + ((long)b * MM + row) * KP + v0 + 4 * u) = *(const uint2*)(&Ls[row * 36 + 4 * u]);
    }
}

// ---------------- hop GEMM: hout[b][m][n] = sum_k X[b][m][k] * A[b][k][n]  (bf16 in/out, f32 acc)
__global__ __launch_bounds__(256, 3) void hop_kernel(
    const float* __restrict__ xin,   // non-null => transpose-stage from x f32
    const u16*  __restrict__ hin,    // non-null => direct bf16 rows (k-contig)
    long h_bstride, int h_rstride,
    const float* __restrict__ Afp,   // non-null => in-kernel transpose of f32 A
    const u16*  __restrict__ At,     // non-null => pre-transposed bf16 A
    long a_bstride,
    u16* __restrict__ hout)
{
    __shared__ __align__(16) u16 smem[25344];   // 50688 B
    u16* As = smem;            // [256][40]
    u16* Xs = smem + 10240;    // [96][40]
    u16* Ct = smem;            // [96][264] epilogue (aliases staging)

    const int t = threadIdx.x;
    const int lane = t & 63;
    const int wv = t >> 6;
    const int n0 = blockIdx.x * NT;
    const int m0 = blockIdx.y * MT;
    const int b  = blockIdx.z;
    const int ln = lane & 15;
    const int q8 = (lane >> 4) * 8;

    f32x4 acc[4][6];
    #pragma unroll
    for (int i = 0; i < 4; ++i)
        #pragma unroll
        for (int j = 0; j < 6; ++j)
            #pragma unroll
            for (int r = 0; r < 4; ++r) acc[i][j][r] = 0.f;

    #pragma unroll 1
    for (int k0 = 0; k0 < KP; k0 += 32) {
        __syncthreads();
        // ---- stage adjacency As[n][k]
        if (At) {
            const u16* Ab = At + (long)b * a_bstride;
            #pragma unroll
            for (int j = 0; j < 8; ++j) {
                int f = t + 256 * j;            // 2048 uint2
                int n = f >> 3, u = f & 7;
                uint2 v = make_uint2(0u, 0u);
                if (n0 + n < NN)
                    v = *(const uint2*)(Ab + (long)(n0 + n) * KP + k0 + 4 * u);
                *(uint2*)(&As[n * AS_S + 4 * u]) = v;
            }
        } else {
            const float* Ab = Afp + (long)b * a_bstride;
            #pragma unroll
            for (int j = 0; j < 4; ++j) {
                int f = t + 256 * j;            // 0..1023
                int kk2 = f >> 6, u = f & 63;
                int k = k0 + 2 * kk2;
                #pragma unroll
                for (int i = 0; i < 4; ++i) {
                    int n = u + 64 * i;
                    float a0 = 0.f, a1 = 0.f;
                    if (n0 + n < NN) {
                        if (k < NN)     a0 = Ab[(long)k * NN + n0 + n];
                        if (k + 1 < NN) a1 = Ab[(long)(k + 1) * NN + n0 + n];
                    }
                    unsigned pk = (unsigned)f2bf(a0) | ((unsigned)f2bf(a1) << 16);
                    *(unsigned*)(&As[n * AS_S + 2 * kk2]) = pk;
                }
            }
        }
        // ---- stage X tile Xs[m][k]
        if (hin) {
            const u16* Hb = hin + (long)b * h_bstride;
            #pragma unroll
            for (int j = 0; j < 3; ++j) {
                int f = t + 256 * j;            // 768 uint2 = 96 rows x 8
                int row = f >> 3, u = f & 7;
                int k = k0 + 4 * u;
                uint2 v = make_uint2(0u, 0u);
                if (k < NN)
                    v = *(const uint2*)(Hb + (long)(m0 + row) * h_rstride + k);
                *(uint2*)(&Xs[row * XS_S + 4 * u]) = v;
            }
        } else {
            const float* xb = xin + ((long)b * CC + (m0 / LLc)) * (NN * LLc);
            #pragma unroll
            for (int j = 0; j < 3; ++j) {
                int f = t + 256 * j;            // 768 float4 = 8c x 96
                int c = f / 96;
                int r = f - c * 96;
                int vl = r / 3;
                int l3 = (r - vl * 3) * 4;
                float4 val = make_float4(0.f, 0.f, 0.f, 0.f);
                if (k0 + vl < NN)
                    val = *(const float4*)(xb + (long)c * (NN * LLc) + (long)(k0 + vl) * LLc + l3);
                int mb = (c * LLc + l3) * XS_S + vl;
                Xs[mb]             = f2bf(val.x);
                Xs[mb + XS_S]      = f2bf(val.y);
                Xs[mb + 2 * XS_S]  = f2bf(val.z);
                Xs[mb + 3 * XS_S]  = f2bf(val.w);
            }
        }
        __syncthreads();
        // ---- MFMA: wave tile 96 x 64 -> 24 mfma per K-step
        bf16x8 af[6];
        #pragma unroll
        for (int i = 0; i < 6; ++i)
            af[i] = *(const bf16x8*)(&Xs[(i * 16 + ln) * XS_S + q8]);
        #pragma unroll
        for (int ns = 0; ns < 4; ++ns) {
            bf16x8 bfr = *(const bf16x8*)(&As[(wv * 64 + ns * 16 + ln) * AS_S + q8]);
            #pragma unroll
            for (int i = 0; i < 6; ++i)
                acc[ns][i] = __builtin_amdgcn_mfma_f32_16x16x32_bf16(af[i], bfr, acc[ns][i], 0, 0, 0);
        }
    }

    __syncthreads();
    // ---- epilogue: acc -> Ct (bf16) -> coalesced global
    #pragma unroll
    for (int ns = 0; ns < 4; ++ns) {
        int col = wv * 64 + ns * 16 + ln;
        #pragma unroll
        for (int i = 0; i < 6; ++i) {
            int rbase = i * 16 + (lane >> 4) * 4;
            #pragma unroll
            for (int r = 0; r < 4; ++r)
                Ct[(rbase + r) * CT_S + col] = f2bf(acc[ns][i][r]);
        }
    }
    __syncthreads();
    u16* Ob = hout + (long)b * ((long)MM * NN);
    #pragma unroll
    for (int j = 0; j < 24; ++j) {
        int f = t + 256 * j;                    // 6144 = 96 rows x 64 uint2
        int row = f >> 6, u = f & 63;
        int n = n0 + 4 * u;
        if (n < NN)
            *(uint2*)(Ob + (long)(m0 + row) * NN + n) = *(const uint2*)(&Ct[row * CT_S + 4 * u]);
    }
}

// ---------------- mix: out[b][o][w][l] (+)= bias + sum_g sum_c W[o][g*32+c] * h_g[b][c][l][w]
__global__ __launch_bounds__(256, 2) void mix_kernel(
    const float* __restrict__ x,     // non-null only when init (group 0)
    const u16* __restrict__ h1,
    const u16* __restrict__ h2,
    const float* __restrict__ W,
    const float* __restrict__ bias,
    int blk1, int blk2,
    float* __restrict__ out, int init)
{
    __shared__ __align__(16) float smem[CC * TS_S + 3 * 1056];
    float* ts = smem;
    float* Ws = smem + CC * TS_S;

    const int t = threadIdx.x;
    const int b = blockIdx.y;
    const int w0 = blockIdx.x * 32;
    const int o  = t & 15;
    const int wg = (t >> 4) & 7;
    const int lh = t >> 7;

    #pragma unroll
    for (int j = 0; j < 4; ++j) {
        int f = t + 256 * j;
        int oo = f & 31, c = f >> 5;
        Ws[c * 33 + oo]        = W[oo * 288 + blk1 * 32 + c];
        Ws[1056 + c * 33 + oo] = W[oo * 288 + blk2 * 32 + c];
        if (init) Ws[2112 + c * 33 + oo] = W[oo * 288 + c];
    }

    float acc2[2][4][6];
    #pragma unroll
    for (int a = 0; a < 2; ++a)
        #pragma unroll
        for (int q = 0; q < 4; ++q)
            #pragma unroll
            for (int l = 0; l < 6; ++l) acc2[a][q][l] = 0.f;

    auto stage_h = [&](const u16* h) {
        #pragma unroll
        for (int j = 0; j < 12; ++j) {
            int f = t + 256 * j;        // 3072 uint2 = 384 rows x 8
            int row = f >> 3, u = f & 7;
            int w = w0 + 4 * u;
            uint2 raw = make_uint2(0u, 0u);
            if (w < NN)
                raw = *(const uint2*)(h + ((long)b * MM + row) * NN + w);
            int c = row / 12;
            int l = row - c * 12;
            float* dst = &ts[c * TS_S + l * 32 + 4 * u];
            dst[0] = bf2f((u16)(raw.x & 0xffffu));
            dst[1] = bf2f((u16)(raw.x >> 16));
            dst[2] = bf2f((u16)(raw.y & 0xffffu));
            dst[3] = bf2f((u16)(raw.y >> 16));
        }
    };
    auto accum = [&](const float* Wg) {
        for (int c = 0; c < CC; ++c) {
            float w1 = Wg[c * 33 + o];
            float w2 = Wg[c * 33 + o + 16];
            #pragma unroll
            for (int l6 = 0; l6 < 6; ++l6) {
                const float4 hv = *(const float4*)(&ts[c * TS_S + (lh * 6 + l6) * 32 + wg * 4]);
                acc2[0][0][l6] += w1 * hv.x;
                acc2[0][1][l6] += w1 * hv.y;
                acc2[0][2][l6] += w1 * hv.z;
                acc2[0][3][l6] += w1 * hv.w;
                acc2[1][0][l6] += w2 * hv.x;
                acc2[1][1][l6] += w2 * hv.y;
                acc2[1][2][l6] += w2 * hv.z;
                acc2[1][3][l6] += w2 * hv.w;
            }
        }
    };

    if (init) {
        // group 0: exact f32 x, transposed [c][w][l] -> ts[c][l][w]
        #pragma unroll
        for (int j = 0; j < 12; ++j) {
            int f = t + 256 * j;        // 3072 float4: 32c x 32w x 3
            int c = f / 96;
            int r = f - c * 96;
            int w = r / 3;
            int q = r - w * 3;
            float4 v = make_float4(0.f, 0.f, 0.f, 0.f);
            if (w0 + w < NN)
                v = *(const float4*)(x + ((long)b * CC + c) * (NN * LLc) + (long)(w0 + w) * LLc + q * 4);
            float* dst = &ts[c * TS_S + (q * 4) * 32 + w];
            dst[0]  = v.x; dst[32] = v.y; dst[64] = v.z; dst[96] = v.w;
        }
        __syncthreads();
        accum(Ws + 2112);
        __syncthreads();
    }
    stage_h(h1);
    __syncthreads();
    accum(Ws);
    __syncthreads();
    stage_h(h2);
    __syncthreads();
    accum(Ws + 1056);

    #pragma unroll
    for (int oh = 0; oh < 2; ++oh) {
        int oo = o + 16 * oh;
        float bs = init ? bias[oo] : 0.f;
        #pragma unroll
        for (int q = 0; q < 4; ++q) {
            int w = w0 + wg * 4 + q;
            if (w < NN) {
                float* op = out + ((long)b * CC + oo) * (NN * LLc) + (long)w * LLc + lh * 6;
                #pragma unroll
                for (int p = 0; p < 3; ++p) {
                    float2* pp = (float2*)op + p;
                    float2 v;
                    if (init) {
                        v.x = bs + acc2[oh][q][2 * p];
                        v.y = bs + acc2[oh][q][2 * p + 1];
                    } else {
                        v = *pp;
                        v.x += acc2[oh][q][2 * p];
                        v.y += acc2[oh][q][2 * p + 1];
                    }
                    *pp = v;
                }
            }
        }
    }
}

extern "C" void kernel_launch(void* const* d_in, const int* in_sizes, int n_in,
                              void* d_out, int out_size, void* d_ws, size_t ws_size,
                              hipStream_t stream) {
    const float* x    = (const float*)d_in[0];
    const float* A0   = (const float*)d_in[1];
    const float* A1   = (const float*)d_in[2];
    const float* A2   = (const float*)d_in[3];
    const float* A3   = (const float*)d_in[4];
    const float* W    = (const float*)d_in[5];
    const float* bias = (const float*)d_in[6];
    float* out = (float*)d_out;

    char* ws = (char*)d_ws;
    const size_t H_BYTES   = (size_t)64 * MM * NN * 2;     // 24,576,000
    const size_t AT_ELS    = (size_t)NN * KP;              // 256,000
    const size_t AT_BYTES  = AT_ELS * 2;                   // 512,000
    const size_t A3T_BYTES = 64 * AT_BYTES;
    const size_t XT_BYTES  = (size_t)64 * MM * KP * 2;     // 25,165,824
    const size_t need_at   = 2 * H_BYTES + 3 * AT_BYTES + A3T_BYTES;   // 83,456,000
    const size_t need_full = need_at + XT_BYTES;                        // 108,621,824
    const bool useAt = ws_size >= need_at;
    const bool useXt = ws_size >= need_full;

    u16* H1 = (u16*)ws;
    u16* H2 = (u16*)(ws + H_BYTES);
    u16* At0 = useAt ? (u16*)(ws + 2 * H_BYTES) : nullptr;
    u16* At1 = useAt ? At0 + AT_ELS : nullptr;
    u16* At2 = useAt ? At1 + AT_ELS : nullptr;
    u16* A3t = useAt ? At2 + AT_ELS : nullptr;
    u16* Xt  = useXt ? (u16*)(ws + need_at) : nullptr;

    dim3 blk(256);
    dim3 hgrid(2, 4, 64);     // n-tiles, m-tiles, batch
    dim3 mgrid(16, 64);

    if (useAt) {
        atrans_kernel<<<dim3(16, 16, 1), blk, 0, stream>>>(A0, 0, At0, 0);
        atrans_kernel<<<dim3(16, 16, 1), blk, 0, stream>>>(A1, 0, At1, 0);
        atrans_kernel<<<dim3(16, 16, 1), blk, 0, stream>>>(A2, 0, At2, 0);
        atrans_kernel<<<dim3(16, 16, 64), blk, 0, stream>>>(A3, (long)NN * NN, A3t, (long)AT_ELS);
    }
    if (useXt) xpose_kernel<<<dim3(16, 64), blk, 0, stream>>>(x, Xt);

    const long XT_BS = (long)MM * KP;
    const long H_BS  = (long)MM * NN;

    const float* Afp[4] = {A0, A1, A2, A3};
    u16* Atp[4] = {At0, At1, At2, A3t};

    for (int i = 0; i < 4; ++i) {
        long a_bs = 0;
        if (i == 3) a_bs = useAt ? (long)AT_ELS : (long)NN * NN;
        const float* af = useAt ? nullptr : Afp[i];
        const u16*   at = useAt ? Atp[i]  : nullptr;
        // hop1: x (or Xt) -> H1
        if (useXt)
            hop_kernel<<<hgrid, blk, 0, stream>>>(nullptr, Xt, XT_BS, KP, af, at, a_bs, H1);
        else
            hop_kernel<<<hgrid, blk, 0, stream>>>(x, nullptr, 0, 0, af, at, a_bs, H1);
        // hop2: H1 -> H2
        hop_kernel<<<hgrid, blk, 0, stream>>>(nullptr, H1, H_BS, NN, af, at, a_bs, H2);
        // mix: accumulate W-blocks (2i+1, 2i+2) [+ group0/bias on first]
        mix_kernel<<<mgrid, blk, 0, stream>>>(i == 0 ? x : nullptr, H1, H2, W, bias,
                                              2 * i + 1, 2 * i + 2, out, i == 0 ? 1 : 0);
    }
}

// Round 3
// 740.040 us; speedup vs baseline: 3.8901x; 1.5716x over previous
//
#include <hip/hip_runtime.h>

typedef unsigned short u16;
typedef __bf16 bf16x8 __attribute__((ext_vector_type(8)));
typedef float f32x4 __attribute__((ext_vector_type(4)));

#define NN 500
#define LLc 12
#define CC 32
#define MM 384          // CC*LLc rows per batch
#define KP 512          // padded K
#define MT 96           // M tile (8 channels * 12)
#define NT 256          // N tile (fallback kernel)
#define NT2 128         // N tile (fast kernel)
#define XS_S 40         // LDS row stride (bf16) for X tile
#define AS_S 40         // LDS row stride (bf16) for A tile
#define CT_S 264        // fallback epilogue C stride
#define CT2_S 136       // fast epilogue C stride (128+8)
#define TS_S 384        // mix LDS c-stride (floats): 12*32

__device__ __forceinline__ u16 f2bf(float f) {
    union { float f; unsigned u; } cv; cv.f = f;
    unsigned u = cv.u;
    u += 0x7fffu + ((u >> 16) & 1u);    // RNE
    return (u16)(u >> 16);
}
__device__ __forceinline__ float bf2f(u16 s) {
    union { unsigned u; float f; } cv; cv.u = ((unsigned)s) << 16;
    return cv.f;
}

// ---------------- pre-pass: A [nb][500][500] f32 -> At [nb][500][512] bf16 transposed
__global__ __launch_bounds__(256) void atrans_kernel(
    const float* __restrict__ A, long in_bstride,
    u16* __restrict__ At, long out_bstride)
{
    __shared__ u16 Ls[32 * 36];
    const int t = threadIdx.x;
    const int n0 = blockIdx.x * 32;
    const int k0 = blockIdx.y * 32;
    const float* Ab = A + (long)blockIdx.z * in_bstride;
    u16* Ob = At + (long)blockIdx.z * out_bstride;
    {
        int vl = t >> 3, u = t & 7;
        float4 v = make_float4(0.f, 0.f, 0.f, 0.f);
        if (k0 + vl < NN && n0 + 4 * u + 4 <= NN)
            v = *(const float4*)(Ab + (long)(k0 + vl) * NN + n0 + 4 * u);
        int nb = 4 * u;
        Ls[(nb + 0) * 36 + vl] = f2bf(v.x);
        Ls[(nb + 1) * 36 + vl] = f2bf(v.y);
        Ls[(nb + 2) * 36 + vl] = f2bf(v.z);
        Ls[(nb + 3) * 36 + vl] = f2bf(v.w);
    }
    __syncthreads();
    {
        int row = t >> 3, u = t & 7;
        if (n0 + row < NN)
            *(uint2*)(Ob + (long)(n0 + row) * KP + k0 + 4 * u) = *(const uint2*)(&Ls[row * 36 + 4 * u]);
    }
}

// ---------------- pre-pass: x [b][32][500][12] f32 -> Xt [b][384][512] bf16 (k=v contiguous)
__global__ __launch_bounds__(256) void xpose_kernel(
    const float* __restrict__ x, u16* __restrict__ Xt)
{
    __shared__ u16 Ls[MM * 36];
    const int t = threadIdx.x;
    const int v0 = blockIdx.x * 32;
    const int b  = blockIdx.y;
    #pragma unroll
    for (int j = 0; j < 12; ++j) {
        int f = t + 256 * j;
        int c = f / 96;
        int r = f - c * 96;
        int vl = r / 3;
        int l3 = (r - vl * 3) * 4;
        float4 v = make_float4(0.f, 0.f, 0.f, 0.f);
        if (v0 + vl < NN)
            v = *(const float4*)(x + ((long)b * CC + c) * (NN * LLc) + (long)(v0 + vl) * LLc + l3);
        int mb = (c * LLc + l3) * 36 + vl;
        Ls[mb]       = f2bf(v.x);
        Ls[mb + 36]  = f2bf(v.y);
        Ls[mb + 72]  = f2bf(v.z);
        Ls[mb + 108] = f2bf(v.w);
    }
    __syncthreads();
    #pragma unroll
    for (int j = 0; j < 12; ++j) {
        int f = t + 256 * j;
        int row = f >> 3, u = f & 7;
        *(uint2*)(Xt + ((long)b * MM + row) * KP + v0 + 4 * u) = *(const uint2*)(&Ls[row * 36 + 4 * u]);
    }
}

// ---------------- fast hop GEMM (bf16 inputs, register-prefetch pipeline)
// hout[b][m][n] = sum_k Xsrc[b][m][k] * At[b][n][k]^T ; grid (4 n-tiles, 4 m-tiles, 64 b)
__global__ __launch_bounds__(256, 4) void hop_fast(
    const u16* __restrict__ Xsrc, long x_bstride, int x_rstride, int x_klim,
    const u16* __restrict__ At,   long a_bstride,
    u16* __restrict__ hout)
{
    __shared__ __align__(16) u16 smem[13056];   // 26112 B (epilogue dominates)
    u16* As = smem;          // [128][40]
    u16* Xs = smem + 5120;   // [96][40]
    u16* Ct = smem;          // [96][136]

    const int t = threadIdx.x;
    const int lane = t & 63;
    const int wv = t >> 6;
    const int n0 = blockIdx.x * NT2;
    const int m0 = blockIdx.y * MT;
    const int b  = blockIdx.z;
    const int ln = lane & 15;
    const int q8 = (lane >> 4) * 8;

    const u16* Ab = At + (long)b * a_bstride;
    const u16* Xb = Xsrc + (long)b * x_bstride;

    uint2 pa[4], px[3];
    auto loadA = [&](int k0) {
        #pragma unroll
        for (int j = 0; j < 4; ++j) {
            int f = t + 256 * j;            // 1024 uint2 = 128 rows x 8
            int n = f >> 3, u = f & 7;
            uint2 v = make_uint2(0u, 0u);
            if (n0 + n < NN)
                v = *(const uint2*)(Ab + (long)(n0 + n) * KP + k0 + 4 * u);
            pa[j] = v;
        }
    };
    auto loadX = [&](int k0) {
        #pragma unroll
        for (int j = 0; j < 3; ++j) {
            int f = t + 256 * j;            // 768 uint2 = 96 rows x 8
            int r = f >> 3, u = f & 7;
            int k = k0 + 4 * u;
            uint2 v = make_uint2(0u, 0u);
            if (k < x_klim)
                v = *(const uint2*)(Xb + (long)(m0 + r) * x_rstride + k);
            px[j] = v;
        }
    };

    f32x4 acc[2][6];
    #pragma unroll
    for (int ns = 0; ns < 2; ++ns)
        #pragma unroll
        for (int i = 0; i < 6; ++i)
            #pragma unroll
            for (int r = 0; r < 4; ++r) acc[ns][i][r] = 0.f;

    loadA(0);
    loadX(0);
    #pragma unroll 1
    for (int s = 0; s < 16; ++s) {
        __syncthreads();                    // LDS readers of previous step done
        // commit prefetched regs -> LDS (compiler inserts the vmcnt wait here,
        // which lands AFTER the previous step's MFMA phase)
        #pragma unroll
        for (int j = 0; j < 4; ++j) {
            int f = t + 256 * j;
            *(uint2*)(&As[(f >> 3) * AS_S + 4 * (f & 7)]) = pa[j];
        }
        #pragma unroll
        for (int j = 0; j < 3; ++j) {
            int f = t + 256 * j;
            *(uint2*)(&Xs[(f >> 3) * XS_S + 4 * (f & 7)]) = px[j];
        }
        if (s < 15) {                       // issue next step's loads (no wait)
            loadA(32 * (s + 1));
            loadX(32 * (s + 1));
        }
        __syncthreads();                    // LDS ready
        bf16x8 af[6];
        #pragma unroll
        for (int i = 0; i < 6; ++i)
            af[i] = *(const bf16x8*)(&Xs[(i * 16 + ln) * XS_S + q8]);
        #pragma unroll
        for (int ns = 0; ns < 2; ++ns) {
            bf16x8 bfr = *(const bf16x8*)(&As[(wv * 32 + ns * 16 + ln) * AS_S + q8]);
            #pragma unroll
            for (int i = 0; i < 6; ++i)
                acc[ns][i] = __builtin_amdgcn_mfma_f32_16x16x32_bf16(af[i], bfr, acc[ns][i], 0, 0, 0);
        }
    }

    __syncthreads();
    #pragma unroll
    for (int ns = 0; ns < 2; ++ns) {
        int col = wv * 32 + ns * 16 + ln;
        #pragma unroll
        for (int i = 0; i < 6; ++i) {
            int rb = i * 16 + (lane >> 4) * 4;
            #pragma unroll
            for (int r = 0; r < 4; ++r)
                Ct[(rb + r) * CT2_S + col] = f2bf(acc[ns][i][r]);
        }
    }
    __syncthreads();
    u16* Ob = hout + (long)b * ((long)MM * NN);
    #pragma unroll
    for (int j = 0; j < 12; ++j) {
        int f = t + 256 * j;                // 3072 = 96 rows x 32 uint2
        int row = f >> 5, u = f & 31;
        int n = n0 + 4 * u;
        if (n < NN)
            *(uint2*)(Ob + (long)(m0 + row) * NN + n) = *(const uint2*)(&Ct[row * CT2_S + 4 * u]);
    }
}

// ---------------- fallback hop GEMM (handles f32 x / f32 A in-kernel) — R2 verbatim
__global__ __launch_bounds__(256, 3) void hop_kernel(
    const float* __restrict__ xin,
    const u16*  __restrict__ hin,
    long h_bstride, int h_rstride,
    const float* __restrict__ Afp,
    const u16*  __restrict__ At,
    long a_bstride,
    u16* __restrict__ hout)
{
    __shared__ __align__(16) u16 smem[25344];
    u16* As = smem;            // [256][40]
    u16* Xs = smem + 10240;    // [96][40]
    u16* Ct = smem;            // [96][264]

    const int t = threadIdx.x;
    const int lane = t & 63;
    const int wv = t >> 6;
    const int n0 = blockIdx.x * NT;
    const int m0 = blockIdx.y * MT;
    const int b  = blockIdx.z;
    const int ln = lane & 15;
    const int q8 = (lane >> 4) * 8;

    f32x4 acc[4][6];
    #pragma unroll
    for (int i = 0; i < 4; ++i)
        #pragma unroll
        for (int j = 0; j < 6; ++j)
            #pragma unroll
            for (int r = 0; r < 4; ++r) acc[i][j][r] = 0.f;

    #pragma unroll 1
    for (int k0 = 0; k0 < KP; k0 += 32) {
        __syncthreads();
        if (At) {
            const u16* Ab = At + (long)b * a_bstride;
            #pragma unroll
            for (int j = 0; j < 8; ++j) {
                int f = t + 256 * j;
                int n = f >> 3, u = f & 7;
                uint2 v = make_uint2(0u, 0u);
                if (n0 + n < NN)
                    v = *(const uint2*)(Ab + (long)(n0 + n) * KP + k0 + 4 * u);
                *(uint2*)(&As[n * AS_S + 4 * u]) = v;
            }
        } else {
            const float* Ab = Afp + (long)b * a_bstride;
            #pragma unroll
            for (int j = 0; j < 4; ++j) {
                int f = t + 256 * j;
                int kk2 = f >> 6, u = f & 63;
                int k = k0 + 2 * kk2;
                #pragma unroll
                for (int i = 0; i < 4; ++i) {
                    int n = u + 64 * i;
                    float a0 = 0.f, a1 = 0.f;
                    if (n0 + n < NN) {
                        if (k < NN)     a0 = Ab[(long)k * NN + n0 + n];
                        if (k + 1 < NN) a1 = Ab[(long)(k + 1) * NN + n0 + n];
                    }
                    unsigned pk = (unsigned)f2bf(a0) | ((unsigned)f2bf(a1) << 16);
                    *(unsigned*)(&As[n * AS_S + 2 * kk2]) = pk;
                }
            }
        }
        if (hin) {
            const u16* Hb = hin + (long)b * h_bstride;
            #pragma unroll
            for (int j = 0; j < 3; ++j) {
                int f = t + 256 * j;
                int row = f >> 3, u = f & 7;
                int k = k0 + 4 * u;
                uint2 v = make_uint2(0u, 0u);
                if (k < NN)
                    v = *(const uint2*)(Hb + (long)(m0 + row) * h_rstride + k);
                *(uint2*)(&Xs[row * XS_S + 4 * u]) = v;
            }
        } else {
            const float* xb = xin + ((long)b * CC + (m0 / LLc)) * (NN * LLc);
            #pragma unroll
            for (int j = 0; j < 3; ++j) {
                int f = t + 256 * j;
                int c = f / 96;
                int r = f - c * 96;
                int vl = r / 3;
                int l3 = (r - vl * 3) * 4;
                float4 val = make_float4(0.f, 0.f, 0.f, 0.f);
                if (k0 + vl < NN)
                    val = *(const float4*)(xb + (long)c * (NN * LLc) + (long)(k0 + vl) * LLc + l3);
                int mb = (c * LLc + l3) * XS_S + vl;
                Xs[mb]             = f2bf(val.x);
                Xs[mb + XS_S]      = f2bf(val.y);
                Xs[mb + 2 * XS_S]  = f2bf(val.z);
                Xs[mb + 3 * XS_S]  = f2bf(val.w);
            }
        }
        __syncthreads();
        bf16x8 af[6];
        #pragma unroll
        for (int i = 0; i < 6; ++i)
            af[i] = *(const bf16x8*)(&Xs[(i * 16 + ln) * XS_S + q8]);
        #pragma unroll
        for (int ns = 0; ns < 4; ++ns) {
            bf16x8 bfr = *(const bf16x8*)(&As[(wv * 64 + ns * 16 + ln) * AS_S + q8]);
            #pragma unroll
            for (int i = 0; i < 6; ++i)
                acc[ns][i] = __builtin_amdgcn_mfma_f32_16x16x32_bf16(af[i], bfr, acc[ns][i], 0, 0, 0);
        }
    }

    __syncthreads();
    #pragma unroll
    for (int ns = 0; ns < 4; ++ns) {
        int col = wv * 64 + ns * 16 + ln;
        #pragma unroll
        for (int i = 0; i < 6; ++i) {
            int rbase = i * 16 + (lane >> 4) * 4;
            #pragma unroll
            for (int r = 0; r < 4; ++r)
                Ct[(rbase + r) * CT_S + col] = f2bf(acc[ns][i][r]);
        }
    }
    __syncthreads();
    u16* Ob = hout + (long)b * ((long)MM * NN);
    #pragma unroll
    for (int j = 0; j < 24; ++j) {
        int f = t + 256 * j;
        int row = f >> 6, u = f & 63;
        int n = n0 + 4 * u;
        if (n < NN)
            *(uint2*)(Ob + (long)(m0 + row) * NN + n) = *(const uint2*)(&Ct[row * CT_S + 4 * u]);
    }
}

// ---------------- mix: out[b][o][w][l] (+)= bias + sum_g sum_c W[o][g*32+c] * h_g[b][c][l][w]
__global__ __launch_bounds__(256, 2) void mix_kernel(
    const float* __restrict__ x,
    const u16* __restrict__ h1,
    const u16* __restrict__ h2,
    const float* __restrict__ W,
    const float* __restrict__ bias,
    int blk1, int blk2,
    float* __restrict__ out, int init)
{
    __shared__ __align__(16) float smem[CC * TS_S + 3 * 1056];
    float* ts = smem;
    float* Ws = smem + CC * TS_S;

    const int t = threadIdx.x;
    const int b = blockIdx.y;
    const int w0 = blockIdx.x * 32;
    const int o  = t & 15;
    const int wg = (t >> 4) & 7;
    const int lh = t >> 7;

    #pragma unroll
    for (int j = 0; j < 4; ++j) {
        int f = t + 256 * j;
        int oo = f & 31, c = f >> 5;
        Ws[c * 33 + oo]        = W[oo * 288 + blk1 * 32 + c];
        Ws[1056 + c * 33 + oo] = W[oo * 288 + blk2 * 32 + c];
        if (init) Ws[2112 + c * 33 + oo] = W[oo * 288 + c];
    }

    float acc2[2][4][6];
    #pragma unroll
    for (int a = 0; a < 2; ++a)
        #pragma unroll
        for (int q = 0; q < 4; ++q)
            #pragma unroll
            for (int l = 0; l < 6; ++l) acc2[a][q][l] = 0.f;

    auto stage_h = [&](const u16* h) {
        #pragma unroll
        for (int j = 0; j < 12; ++j) {
            int f = t + 256 * j;
            int row = f >> 3, u = f & 7;
            int w = w0 + 4 * u;
            uint2 raw = make_uint2(0u, 0u);
            if (w < NN)
                raw = *(const uint2*)(h + ((long)b * MM + row) * NN + w);
            int c = row / 12;
            int l = row - c * 12;
            float* dst = &ts[c * TS_S + l * 32 + 4 * u];
            dst[0] = bf2f((u16)(raw.x & 0xffffu));
            dst[1] = bf2f((u16)(raw.x >> 16));
            dst[2] = bf2f((u16)(raw.y & 0xffffu));
            dst[3] = bf2f((u16)(raw.y >> 16));
        }
    };
    auto accum = [&](const float* Wg) {
        for (int c = 0; c < CC; ++c) {
            float w1 = Wg[c * 33 + o];
            float w2 = Wg[c * 33 + o + 16];
            #pragma unroll
            for (int l6 = 0; l6 < 6; ++l6) {
                const float4 hv = *(const float4*)(&ts[c * TS_S + (lh * 6 + l6) * 32 + wg * 4]);
                acc2[0][0][l6] += w1 * hv.x;
                acc2[0][1][l6] += w1 * hv.y;
                acc2[0][2][l6] += w1 * hv.z;
                acc2[0][3][l6] += w1 * hv.w;
                acc2[1][0][l6] += w2 * hv.x;
                acc2[1][1][l6] += w2 * hv.y;
                acc2[1][2][l6] += w2 * hv.z;
                acc2[1][3][l6] += w2 * hv.w;
            }
        }
    };

    if (init) {
        #pragma unroll
        for (int j = 0; j < 12; ++j) {
            int f = t + 256 * j;
            int c = f / 96;
            int r = f - c * 96;
            int w = r / 3;
            int q = r - w * 3;
            float4 v = make_float4(0.f, 0.f, 0.f, 0.f);
            if (w0 + w < NN)
                v = *(const float4*)(x + ((long)b * CC + c) * (NN * LLc) + (long)(w0 + w) * LLc + q * 4);
            float* dst = &ts[c * TS_S + (q * 4) * 32 + w];
            dst[0]  = v.x; dst[32] = v.y; dst[64] = v.z; dst[96] = v.w;
        }
        __syncthreads();
        accum(Ws + 2112);
        __syncthreads();
    }
    stage_h(h1);
    __syncthreads();
    accum(Ws);
    __syncthreads();
    stage_h(h2);
    __syncthreads();
    accum(Ws + 1056);

    #pragma unroll
    for (int oh = 0; oh < 2; ++oh) {
        int oo = o + 16 * oh;
        float bs = init ? bias[oo] : 0.f;
        #pragma unroll
        for (int q = 0; q < 4; ++q) {
            int w = w0 + wg * 4 + q;
            if (w < NN) {
                float* op = out + ((long)b * CC + oo) * (NN * LLc) + (long)w * LLc + lh * 6;
                #pragma unroll
                for (int p = 0; p < 3; ++p) {
                    float2* pp = (float2*)op + p;
                    float2 v;
                    if (init) {
                        v.x = bs + acc2[oh][q][2 * p];
                        v.y = bs + acc2[oh][q][2 * p + 1];
                    } else {
                        v = *pp;
                        v.x += acc2[oh][q][2 * p];
                        v.y += acc2[oh][q][2 * p + 1];
                    }
                    *pp = v;
                }
            }
        }
    }
}

extern "C" void kernel_launch(void* const* d_in, const int* in_sizes, int n_in,
                              void* d_out, int out_size, void* d_ws, size_t ws_size,
                              hipStream_t stream) {
    const float* x    = (const float*)d_in[0];
    const float* A0   = (const float*)d_in[1];
    const float* A1   = (const float*)d_in[2];
    const float* A2   = (const float*)d_in[3];
    const float* A3   = (const float*)d_in[4];
    const float* W    = (const float*)d_in[5];
    const float* bias = (const float*)d_in[6];
    float* out = (float*)d_out;

    char* ws = (char*)d_ws;
    const size_t H_BYTES   = (size_t)64 * MM * NN * 2;     // 24,576,000
    const size_t AT_ELS    = (size_t)NN * KP;              // 256,000
    const size_t AT_BYTES  = AT_ELS * 2;
    const size_t A3T_BYTES = 64 * AT_BYTES;
    const size_t XT_BYTES  = (size_t)64 * MM * KP * 2;     // 25,165,824
    const size_t need_at   = 2 * H_BYTES + 3 * AT_BYTES + A3T_BYTES;
    const size_t need_full = need_at + XT_BYTES;           // 108,621,824 (proven OK in R2)
    const bool useAt = ws_size >= need_at;
    const bool useXt = ws_size >= need_full;

    u16* H1 = (u16*)ws;
    u16* H2 = (u16*)(ws + H_BYTES);
    u16* At0 = useAt ? (u16*)(ws + 2 * H_BYTES) : nullptr;
    u16* At1 = useAt ? At0 + AT_ELS : nullptr;
    u16* At2 = useAt ? At1 + AT_ELS : nullptr;
    u16* A3t = useAt ? At2 + AT_ELS : nullptr;
    u16* Xt  = useXt ? (u16*)(ws + need_at) : nullptr;

    dim3 blk(256);
    dim3 fgrid(4, 4, 64);     // fast hop: 1024 blocks
    dim3 hgrid(2, 4, 64);     // fallback hop
    dim3 mgrid(16, 64);

    if (useXt) xpose_kernel<<<dim3(16, 64), blk, 0, stream>>>(x, Xt);
    if (useAt) {
        atrans_kernel<<<dim3(16, 16, 1), blk, 0, stream>>>(A0, 0, At0, 0);
        atrans_kernel<<<dim3(16, 16, 1), blk, 0, stream>>>(A1, 0, At1, 0);
        atrans_kernel<<<dim3(16, 16, 1), blk, 0, stream>>>(A2, 0, At2, 0);
        atrans_kernel<<<dim3(16, 16, 64), blk, 0, stream>>>(A3, (long)NN * NN, A3t, (long)AT_ELS);
    }

    const long XT_BS = (long)MM * KP;
    const long H_BS  = (long)MM * NN;

    const float* Afp[4] = {A0, A1, A2, A3};
    u16* Atp[4] = {At0, At1, At2, A3t};

    for (int i = 0; i < 4; ++i) {
        if (useAt && useXt) {
            long a_bs = (i == 3) ? (long)AT_ELS : 0;
            hop_fast<<<fgrid, blk, 0, stream>>>(Xt, XT_BS, KP, KP, Atp[i], a_bs, H1);
            hop_fast<<<fgrid, blk, 0, stream>>>(H1, H_BS, NN, NN, Atp[i], a_bs, H2);
        } else {
            long a_bs = 0;
            if (i == 3) a_bs = useAt ? (long)AT_ELS : (long)NN * NN;
            const float* af = useAt ? nullptr : Afp[i];
            const u16*   at = useAt ? Atp[i]  : nullptr;
            hop_kernel<<<hgrid, blk, 0, stream>>>(x, nullptr, 0, 0, af, at, a_bs, H1);
            hop_kernel<<<hgrid, blk, 0, stream>>>(nullptr, H1, H_BS, NN, af, at, a_bs, H2);
        }
        mix_kernel<<<mgrid, blk, 0, stream>>>(i == 0 ? x : nullptr, H1, H2, W, bias,
                                              2 * i + 1, 2 * i + 2, out, i == 0 ? 1 : 0);
    }
}

// Round 6
// 545.958 us; speedup vs baseline: 5.2730x; 1.3555x over previous
//
#include <hip/hip_runtime.h>

typedef unsigned short u16;
typedef __bf16 bf16x8 __attribute__((ext_vector_type(8)));
typedef float f32x4 __attribute__((ext_vector_type(4)));

#define NN 500
#define LLc 12
#define CC 32
#define MM 384          // CC*LLc rows per batch
#define KP 512          // padded K
#define MT 96           // M tile (8 channels * 12)
#define NT2 128         // N tile
#define XS_S 40         // LDS row stride (bf16) for X tile
#define AS_S 40         // LDS row stride (bf16) for A tile
#define CT2_S 136       // epilogue C stride
#define TS_S 384        // fallback mix LDS c-stride (floats)
#define AT_ELS 256000   // NN*KP

__device__ __forceinline__ u16 f2bf(float f) {
    union { float f; unsigned u; } cv; cv.f = f;
    unsigned u = cv.u;
    u += 0x7fffu + ((u >> 16) & 1u);    // RNE
    return (u16)(u >> 16);
}
__device__ __forceinline__ float bf2f(u16 s) {
    union { unsigned u; float f; } cv; cv.u = ((unsigned)s) << 16;
    return cv.f;
}

// ---------------- merged A-transpose: z=0,1,2 -> At_s + z*AT_ELS; z>=3 -> At_b + (z-3)*AT_ELS
__global__ __launch_bounds__(256) void atrans_all(
    const float* __restrict__ A0, const float* __restrict__ A1,
    const float* __restrict__ A2, const float* __restrict__ A3,
    u16* __restrict__ At_s, u16* __restrict__ At_b)
{
    __shared__ u16 Ls[32 * 36];
    const int t = threadIdx.x;
    const int n0 = blockIdx.x * 32;
    const int k0 = blockIdx.y * 32;
    const int z = blockIdx.z;
    const float* Ab; u16* Ob;
    if (z == 0)      { Ab = A0; Ob = At_s; }
    else if (z == 1) { Ab = A1; Ob = At_s + (long)AT_ELS; }
    else if (z == 2) { Ab = A2; Ob = At_s + 2L * AT_ELS; }
    else             { Ab = A3 + (long)(z - 3) * NN * NN; Ob = At_b + (long)(z - 3) * AT_ELS; }
    {
        int vl = t >> 3, u = t & 7;
        float4 v = make_float4(0.f, 0.f, 0.f, 0.f);
        if (k0 + vl < NN && n0 + 4 * u + 4 <= NN)
            v = *(const float4*)(Ab + (long)(k0 + vl) * NN + n0 + 4 * u);
        int nb = 4 * u;
        Ls[(nb + 0) * 36 + vl] = f2bf(v.x);
        Ls[(nb + 1) * 36 + vl] = f2bf(v.y);
        Ls[(nb + 2) * 36 + vl] = f2bf(v.z);
        Ls[(nb + 3) * 36 + vl] = f2bf(v.w);
    }
    __syncthreads();
    {
        int row = t >> 3, u = t & 7;
        if (n0 + row < NN)
            *(uint2*)(Ob + (long)(n0 + row) * KP + k0 + 4 * u) = *(const uint2*)(&Ls[row * 36 + 4 * u]);
    }
}

// ---------------- pre-pass: x f32 -> Xt [b][384][512] bf16 (k=v contiguous, zero-padded)
__global__ __launch_bounds__(256) void xpose_kernel(
    const float* __restrict__ x, u16* __restrict__ Xt)
{
    __shared__ u16 Ls[MM * 36];
    const int t = threadIdx.x;
    const int v0 = blockIdx.x * 32;
    const int b  = blockIdx.y;
    #pragma unroll
    for (int j = 0; j < 12; ++j) {
        int f = t + 256 * j;
        int c = f / 96;
        int r = f - c * 96;
        int vl = r / 3;
        int l3 = (r - vl * 3) * 4;
        float4 v = make_float4(0.f, 0.f, 0.f, 0.f);
        if (v0 + vl < NN)
            v = *(const float4*)(x + ((long)b * CC + c) * (NN * LLc) + (long)(v0 + vl) * LLc + l3);
        int mb = (c * LLc + l3) * 36 + vl;
        Ls[mb]       = f2bf(v.x);
        Ls[mb + 36]  = f2bf(v.y);
        Ls[mb + 72]  = f2bf(v.z);
        Ls[mb + 108] = f2bf(v.w);
    }
    __syncthreads();
    #pragma unroll
    for (int j = 0; j < 12; ++j) {
        int f = t + 256 * j;
        int row = f >> 3, u = f & 7;
        *(uint2*)(Xt + ((long)b * MM + row) * KP + v0 + 4 * u) = *(const uint2*)(&Ls[row * 36 + 4 * u]);
    }
}

// ---------------- merged hop GEMM: 4 adjacencies in one launch (z = b*4 + g)
__global__ __launch_bounds__(256, 4) void hop_fast2(
    const u16* __restrict__ Xsrc, long x_gstride, long x_bstride, int x_rstride, int x_klim,
    const u16* __restrict__ At_s,   // g<3: static A, g-stride AT_ELS
    const u16* __restrict__ At_b,   // g==3: batched A, b-stride AT_ELS
    u16* __restrict__ Hout, long h_gstride)
{
    __shared__ __align__(16) u16 smem[13056];
    u16* As = smem;          // [128][40]
    u16* Xs = smem + 5120;   // [96][40]
    u16* Ct = smem;          // [96][136]

    const int t = threadIdx.x;
    const int lane = t & 63;
    const int wv = t >> 6;
    const int n0 = blockIdx.x * NT2;
    const int m0 = blockIdx.y * MT;
    const int g  = blockIdx.z & 3;
    const int b  = blockIdx.z >> 2;
    const int ln = lane & 15;
    const int q8 = (lane >> 4) * 8;

    const u16* Ab = (g < 3) ? (At_s + (long)g * AT_ELS) : (At_b + (long)b * AT_ELS);
    const u16* Xb = Xsrc + (long)g * x_gstride + (long)b * x_bstride;
    u16* Ob = Hout + (long)g * h_gstride + (long)b * ((long)MM * NN);

    uint2 pa[4], px[3];
    auto loadA = [&](int k0) {
        #pragma unroll
        for (int j = 0; j < 4; ++j) {
            int f = t + 256 * j;
            int n = f >> 3, u = f & 7;
            uint2 v = make_uint2(0u, 0u);
            if (n0 + n < NN)
                v = *(const uint2*)(Ab + (long)(n0 + n) * KP + k0 + 4 * u);
            pa[j] = v;
        }
    };
    auto loadX = [&](int k0) {
        #pragma unroll
        for (int j = 0; j < 3; ++j) {
            int f = t + 256 * j;
            int r = f >> 3, u = f & 7;
            int k = k0 + 4 * u;
            uint2 v = make_uint2(0u, 0u);
            if (k < x_klim)
                v = *(const uint2*)(Xb + (long)(m0 + r) * x_rstride + k);
            px[j] = v;
        }
    };

    f32x4 acc[2][6];
    #pragma unroll
    for (int ns = 0; ns < 2; ++ns)
        #pragma unroll
        for (int i = 0; i < 6; ++i)
            #pragma unroll
            for (int r = 0; r < 4; ++r) acc[ns][i][r] = 0.f;

    loadA(0);
    loadX(0);
    #pragma unroll 1
    for (int s = 0; s < 16; ++s) {
        __syncthreads();
        #pragma unroll
        for (int j = 0; j < 4; ++j) {
            int f = t + 256 * j;
            *(uint2*)(&As[(f >> 3) * AS_S + 4 * (f & 7)]) = pa[j];
        }
        #pragma unroll
        for (int j = 0; j < 3; ++j) {
            int f = t + 256 * j;
            *(uint2*)(&Xs[(f >> 3) * XS_S + 4 * (f & 7)]) = px[j];
        }
        if (s < 15) {
            loadA(32 * (s + 1));
            loadX(32 * (s + 1));
        }
        __syncthreads();
        bf16x8 af[6];
        #pragma unroll
        for (int i = 0; i < 6; ++i)
            af[i] = *(const bf16x8*)(&Xs[(i * 16 + ln) * XS_S + q8]);
        #pragma unroll
        for (int ns = 0; ns < 2; ++ns) {
            bf16x8 bfr = *(const bf16x8*)(&As[(wv * 32 + ns * 16 + ln) * AS_S + q8]);
            #pragma unroll
            for (int i = 0; i < 6; ++i)
                acc[ns][i] = __builtin_amdgcn_mfma_f32_16x16x32_bf16(af[i], bfr, acc[ns][i], 0, 0, 0);
        }
    }

    __syncthreads();
    #pragma unroll
    for (int ns = 0; ns < 2; ++ns) {
        int col = wv * 32 + ns * 16 + ln;
        #pragma unroll
        for (int i = 0; i < 6; ++i) {
            int rb = i * 16 + (lane >> 4) * 4;
            #pragma unroll
            for (int r = 0; r < 4; ++r)
                Ct[(rb + r) * CT2_S + col] = f2bf(acc[ns][i][r]);
        }
    }
    __syncthreads();
    #pragma unroll
    for (int j = 0; j < 12; ++j) {
        int f = t + 256 * j;
        int row = f >> 5, u = f & 31;
        int n = n0 + 4 * u;
        if (n < NN)
            *(uint2*)(Ob + (long)(m0 + row) * NN + n) = *(const uint2*)(&Ct[row * CT2_S + 4 * u]);
    }
}

// ---------------- single-pass mix: out = bias + W0*Xt + sum over 8 hop buffers
// grid (16 w-tiles, 64 b); chunked c-staging with register prefetch; write-only out.
__global__ __launch_bounds__(256, 3) void mix_all(
    const u16* __restrict__ Xt,
    const u16* __restrict__ H,      // 8 buffers: [H1_0..H1_3, H2_0..H2_3]
    const float* __restrict__ W,
    const float* __restrict__ bias,
    float* __restrict__ out)
{
    __shared__ __align__(16) float smem[96 * 36 + 288 * 33];   // 13824 + 38016 B
    float* ts = smem;              // chunk tile [96 rows (c,l)][36]
    float* Ws = smem + 96 * 36;    // [288 cidx][33] = W[o][cidx] transposed

    const int t  = threadIdx.x;
    const int b  = blockIdx.y;
    const int w0 = blockIdx.x * 32;
    const int o  = t & 31;
    const int wq = t >> 5;
    const int w4 = wq * 4;
    const long HBUF = (long)64 * MM * NN;

    // stage all W transposed: Ws[cidx][o]
    #pragma unroll
    for (int j = 0; j < 36; ++j) {
        int f = t + 256 * j;           // 0..9215
        int oo = f & 31, ci = f >> 5;
        Ws[ci * 33 + oo] = W[oo * 288 + ci];
    }

    float acc[4][12];
    #pragma unroll
    for (int k = 0; k < 4; ++k)
        #pragma unroll
        for (int l = 0; l < 12; ++l) acc[k][l] = 0.f;

    uint2 px[3];
    auto loadq = [&](int q) {
        int g = q >> 2, c0 = (q & 3) << 3;
        const u16* base; int rs;
        if (g == 0) { base = Xt + (long)b * (MM * KP); rs = KP; }
        else {
            int gg = g - 1, i = gg >> 1;
            int buf = (gg & 1) ? 4 + i : i;
            base = H + (long)buf * HBUF + (long)b * ((long)MM * NN); rs = NN;
        }
        int m0c = c0 * 12;
        #pragma unroll
        for (int j = 0; j < 3; ++j) {
            int f = t + 256 * j;       // 768 uint2 = 96 rows x 8
            int r = f >> 3, u = f & 7;
            px[j] = *(const uint2*)(base + (long)(m0c + r) * rs + w0 + 4 * u);
        }
    };

    loadq(0);
    #pragma unroll 1
    for (int q = 0; q < 36; ++q) {
        __syncthreads();               // prior chunk's ts reads done
        #pragma unroll
        for (int j = 0; j < 3; ++j) {  // commit (vmcnt wait lands here)
            int f = t + 256 * j;
            int r = f >> 3, u = f & 7;
            uint2 raw = px[j];
            float4 v = make_float4(bf2f((u16)(raw.x & 0xffffu)), bf2f((u16)(raw.x >> 16)),
                                   bf2f((u16)(raw.y & 0xffffu)), bf2f((u16)(raw.y >> 16)));
            *(float4*)(&ts[r * 36 + 4 * u]) = v;
        }
        if (q < 35) loadq(q + 1);
        __syncthreads();
        int g = q >> 2, c0 = (q & 3) << 3;
        #pragma unroll 1
        for (int cl = 0; cl < 8; ++cl) {
            float wgt = Ws[(g * 32 + c0 + cl) * 33 + o];
            #pragma unroll
            for (int l = 0; l < 12; ++l) {
                float4 h = *(const float4*)(&ts[(cl * 12 + l) * 36 + w4]);
                acc[0][l] += wgt * h.x;
                acc[1][l] += wgt * h.y;
                acc[2][l] += wgt * h.z;
                acc[3][l] += wgt * h.w;
            }
        }
    }

    // epilogue: 4 rounds of 8 o's via LDS (coalesced out stores; bias added here)
    #pragma unroll 1
    for (int r = 0; r < 4; ++r) {
        __syncthreads();
        if ((o >> 3) == r) {
            int ol = o & 7;
            #pragma unroll
            for (int k = 0; k < 4; ++k)
                #pragma unroll
                for (int l = 0; l < 12; ++l)
                    ts[ol * 388 + (w4 + k) * 12 + l] = acc[k][l];
        }
        __syncthreads();
        #pragma unroll
        for (int j = 0; j < 3; ++j) {
            int f4 = t + 256 * j;          // 0..767 float4 = 8o x 32w x 3
            int ol = f4 / 96;
            int rem = f4 - ol * 96;
            int w  = rem / 3;
            int lq = rem - w * 3;
            if (w0 + w < NN) {
                float4 v = *(const float4*)(&ts[ol * 388 + w * 12 + lq * 4]);
                float bs = bias[r * 8 + ol];
                v.x += bs; v.y += bs; v.z += bs; v.w += bs;
                *(float4*)(out + (((long)b * CC + r * 8 + ol) * NN + w0 + w) * LLc + lq * 4) = v;
            }
        }
    }
}

// ======================================================================
// Fallback path (R3-equivalent, ~740 us) — used when ws < 256 MB tier
// ======================================================================
__global__ __launch_bounds__(256, 4) void hop_fast(
    const u16* __restrict__ Xsrc, long x_bstride, int x_rstride, int x_klim,
    const u16* __restrict__ At,   long a_bstride,
    u16* __restrict__ hout)
{
    __shared__ __align__(16) u16 smem[13056];
    u16* As = smem;
    u16* Xs = smem + 5120;
    u16* Ct = smem;

    const int t = threadIdx.x;
    const int lane = t & 63;
    const int wv = t >> 6;
    const int n0 = blockIdx.x * NT2;
    const int m0 = blockIdx.y * MT;
    const int b  = blockIdx.z;
    const int ln = lane & 15;
    const int q8 = (lane >> 4) * 8;

    const u16* Ab = At + (long)b * a_bstride;
    const u16* Xb = Xsrc + (long)b * x_bstride;

    uint2 pa[4], px[3];
    auto loadA = [&](int k0) {
        #pragma unroll
        for (int j = 0; j < 4; ++j) {
            int f = t + 256 * j;
            int n = f >> 3, u = f & 7;
            uint2 v = make_uint2(0u, 0u);
            if (n0 + n < NN)
                v = *(const uint2*)(Ab + (long)(n0 + n) * KP + k0 + 4 * u);
            pa[j] = v;
        }
    };
    auto loadX = [&](int k0) {
        #pragma unroll
        for (int j = 0; j < 3; ++j) {
            int f = t + 256 * j;
            int r = f >> 3, u = f & 7;
            int k = k0 + 4 * u;
            uint2 v = make_uint2(0u, 0u);
            if (k < x_klim)
                v = *(const uint2*)(Xb + (long)(m0 + r) * x_rstride + k);
            px[j] = v;
        }
    };

    f32x4 acc[2][6];
    #pragma unroll
    for (int ns = 0; ns < 2; ++ns)
        #pragma unroll
        for (int i = 0; i < 6; ++i)
            #pragma unroll
            for (int r = 0; r < 4; ++r) acc[ns][i][r] = 0.f;

    loadA(0);
    loadX(0);
    #pragma unroll 1
    for (int s = 0; s < 16; ++s) {
        __syncthreads();
        #pragma unroll
        for (int j = 0; j < 4; ++j) {
            int f = t + 256 * j;
            *(uint2*)(&As[(f >> 3) * AS_S + 4 * (f & 7)]) = pa[j];
        }
        #pragma unroll
        for (int j = 0; j < 3; ++j) {
            int f = t + 256 * j;
            *(uint2*)(&Xs[(f >> 3) * XS_S + 4 * (f & 7)]) = px[j];
        }
        if (s < 15) {
            loadA(32 * (s + 1));
            loadX(32 * (s + 1));
        }
        __syncthreads();
        bf16x8 af[6];
        #pragma unroll
        for (int i = 0; i < 6; ++i)
            af[i] = *(const bf16x8*)(&Xs[(i * 16 + ln) * XS_S + q8]);
        #pragma unroll
        for (int ns = 0; ns < 2; ++ns) {
            bf16x8 bfr = *(const bf16x8*)(&As[(wv * 32 + ns * 16 + ln) * AS_S + q8]);
            #pragma unroll
            for (int i = 0; i < 6; ++i)
                acc[ns][i] = __builtin_amdgcn_mfma_f32_16x16x32_bf16(af[i], bfr, acc[ns][i], 0, 0, 0);
        }
    }

    __syncthreads();
    #pragma unroll
    for (int ns = 0; ns < 2; ++ns) {
        int col = wv * 32 + ns * 16 + ln;
        #pragma unroll
        for (int i = 0; i < 6; ++i) {
            int rb = i * 16 + (lane >> 4) * 4;
            #pragma unroll
            for (int r = 0; r < 4; ++r)
                Ct[(rb + r) * CT2_S + col] = f2bf(acc[ns][i][r]);
        }
    }
    __syncthreads();
    u16* Ob = hout + (long)b * ((long)MM * NN);
    #pragma unroll
    for (int j = 0; j < 12; ++j) {
        int f = t + 256 * j;
        int row = f >> 5, u = f & 31;
        int n = n0 + 4 * u;
        if (n < NN)
            *(uint2*)(Ob + (long)(m0 + row) * NN + n) = *(const uint2*)(&Ct[row * CT2_S + 4 * u]);
    }
}

__global__ __launch_bounds__(256, 2) void mix_kernel(
    const float* __restrict__ x,
    const u16* __restrict__ h1,
    const u16* __restrict__ h2,
    const float* __restrict__ W,
    const float* __restrict__ bias,
    int blk1, int blk2,
    float* __restrict__ out, int init)
{
    __shared__ __align__(16) float smem[CC * TS_S + 3 * 1056];
    float* ts = smem;
    float* Ws = smem + CC * TS_S;

    const int t = threadIdx.x;
    const int b = blockIdx.y;
    const int w0 = blockIdx.x * 32;
    const int o  = t & 15;
    const int wg = (t >> 4) & 7;
    const int lh = t >> 7;

    #pragma unroll
    for (int j = 0; j < 4; ++j) {
        int f = t + 256 * j;
        int oo = f & 31, c = f >> 5;
        Ws[c * 33 + oo]        = W[oo * 288 + blk1 * 32 + c];
        Ws[1056 + c * 33 + oo] = W[oo * 288 + blk2 * 32 + c];
        if (init) Ws[2112 + c * 33 + oo] = W[oo * 288 + c];
    }

    float acc2[2][4][6];
    #pragma unroll
    for (int a = 0; a < 2; ++a)
        #pragma unroll
        for (int q = 0; q < 4; ++q)
            #pragma unroll
            for (int l = 0; l < 6; ++l) acc2[a][q][l] = 0.f;

    auto stage_h = [&](const u16* h) {
        #pragma unroll
        for (int j = 0; j < 12; ++j) {
            int f = t + 256 * j;
            int row = f >> 3, u = f & 7;
            int w = w0 + 4 * u;
            uint2 raw = make_uint2(0u, 0u);
            if (w < NN)
                raw = *(const uint2*)(h + ((long)b * MM + row) * NN + w);
            int c = row / 12;
            int l = row - c * 12;
            float* dst = &ts[c * TS_S + l * 32 + 4 * u];
            dst[0] = bf2f((u16)(raw.x & 0xffffu));
            dst[1] = bf2f((u16)(raw.x >> 16));
            dst[2] = bf2f((u16)(raw.y & 0xffffu));
            dst[3] = bf2f((u16)(raw.y >> 16));
        }
    };
    auto accum = [&](const float* Wg) {
        for (int c = 0; c < CC; ++c) {
            float w1 = Wg[c * 33 + o];
            float w2 = Wg[c * 33 + o + 16];
            #pragma unroll
            for (int l6 = 0; l6 < 6; ++l6) {
                const float4 hv = *(const float4*)(&ts[c * TS_S + (lh * 6 + l6) * 32 + wg * 4]);
                acc2[0][0][l6] += w1 * hv.x;
                acc2[0][1][l6] += w1 * hv.y;
                acc2[0][2][l6] += w1 * hv.z;
                acc2[0][3][l6] += w1 * hv.w;
                acc2[1][0][l6] += w2 * hv.x;
                acc2[1][1][l6] += w2 * hv.y;
                acc2[1][2][l6] += w2 * hv.z;
                acc2[1][3][l6] += w2 * hv.w;
            }
        }
    };

    if (init) {
        #pragma unroll
        for (int j = 0; j < 12; ++j) {
            int f = t + 256 * j;
            int c = f / 96;
            int r = f - c * 96;
            int w = r / 3;
            int q = r - w * 3;
            float4 v = make_float4(0.f, 0.f, 0.f, 0.f);
            if (w0 + w < NN)
                v = *(const float4*)(x + ((long)b * CC + c) * (NN * LLc) + (long)(w0 + w) * LLc + q * 4);
            float* dst = &ts[c * TS_S + (q * 4) * 32 + w];
            dst[0]  = v.x; dst[32] = v.y; dst[64] = v.z; dst[96] = v.w;
        }
        __syncthreads();
        accum(Ws + 2112);
        __syncthreads();
    }
    stage_h(h1);
    __syncthreads();
    accum(Ws);
    __syncthreads();
    stage_h(h2);
    __syncthreads();
    accum(Ws + 1056);

    #pragma unroll
    for (int oh = 0; oh < 2; ++oh) {
        int oo = o + 16 * oh;
        float bs = init ? bias[oo] : 0.f;
        #pragma unroll
        for (int q = 0; q < 4; ++q) {
            int w = w0 + wg * 4 + q;
            if (w < NN) {
                float* op = out + ((long)b * CC + oo) * (NN * LLc) + (long)w * LLc + lh * 6;
                #pragma unroll
                for (int p = 0; p < 3; ++p) {
                    float2* pp = (float2*)op + p;
                    float2 v;
                    if (init) {
                        v.x = bs + acc2[oh][q][2 * p];
                        v.y = bs + acc2[oh][q][2 * p + 1];
                    } else {
                        v = *pp;
                        v.x += acc2[oh][q][2 * p];
                        v.y += acc2[oh][q][2 * p + 1];
                    }
                    *pp = v;
                }
            }
        }
    }
}

extern "C" void kernel_launch(void* const* d_in, const int* in_sizes, int n_in,
                              void* d_out, int out_size, void* d_ws, size_t ws_size,
                              hipStream_t stream) {
    const float* x    = (const float*)d_in[0];
    const float* A0   = (const float*)d_in[1];
    const float* A1   = (const float*)d_in[2];
    const float* A2   = (const float*)d_in[3];
    const float* A3   = (const float*)d_in[4];
    const float* W    = (const float*)d_in[5];
    const float* bias = (const float*)d_in[6];
    float* out = (float*)d_out;
    char* ws = (char*)d_ws;

    const size_t HBUF_ELS  = (size_t)64 * MM * NN;          // 12,288,000
    const size_t H8_BYTES  = 8 * HBUF_ELS * 2;              // 196,608,000
    const size_t AT_BYTES  = (size_t)AT_ELS * 2;            // 512,000
    const size_t A3T_BYTES = 64 * AT_BYTES;                 // 32,768,000
    const size_t XT_BYTES  = (size_t)64 * MM * KP * 2;      // 25,165,824
    const size_t need2 = H8_BYTES + 3 * AT_BYTES + A3T_BYTES + XT_BYTES;  // 256,077,824

    dim3 blk(256);

    if (ws_size >= need2) {
        // ---------- fast path: 8 H buffers, merged launches, single mix ----------
        u16* H    = (u16*)ws;
        u16* At_s = (u16*)(ws + H8_BYTES);
        u16* A3t  = At_s + 3L * AT_ELS;
        u16* Xt   = (u16*)(ws + H8_BYTES + 3 * AT_BYTES + A3T_BYTES);

        atrans_all<<<dim3(16, 16, 67), blk, 0, stream>>>(A0, A1, A2, A3, At_s, A3t);
        xpose_kernel<<<dim3(16, 64), blk, 0, stream>>>(x, Xt);
        // hop1 for all 4 adjacencies: Xt -> H[0..3]
        hop_fast2<<<dim3(4, 4, 256), blk, 0, stream>>>(
            Xt, 0L, (long)MM * KP, KP, KP, At_s, A3t, H, (long)HBUF_ELS);
        // hop2: H[g] -> H[4+g]
        hop_fast2<<<dim3(4, 4, 256), blk, 0, stream>>>(
            H, (long)HBUF_ELS, (long)MM * NN, NN, NN, At_s, A3t,
            H + 4 * HBUF_ELS, (long)HBUF_ELS);
        // single-pass mix (writes out exactly once, bias included)
        mix_all<<<dim3(16, 64), blk, 0, stream>>>(Xt, H, W, bias, out);
        return;
    }

    // ---------- fallback (R3 path) ----------
    const size_t H_BYTES   = HBUF_ELS * 2;                  // 24,576,000
    const size_t need_at   = 2 * H_BYTES + 3 * AT_BYTES + A3T_BYTES;
    const size_t need_full = need_at + XT_BYTES;            // 108,621,824 (proven OK in R2/R3)

    u16* H1 = (u16*)ws;
    u16* H2 = (u16*)(ws + H_BYTES);
    u16* At0 = (u16*)(ws + 2 * H_BYTES);                    // At0..At2 contiguous
    u16* A3t = At0 + 3L * AT_ELS;
    u16* Xt  = (u16*)(ws + need_at);
    (void)need_full;

    dim3 fgrid(4, 4, 64);
    dim3 mgrid(16, 64);

    xpose_kernel<<<dim3(16, 64), blk, 0, stream>>>(x, Xt);
    atrans_all<<<dim3(16, 16, 67), blk, 0, stream>>>(A0, A1, A2, A3, At0, A3t);

    const long XT_BS = (long)MM * KP;
    const long H_BS  = (long)MM * NN;
    u16* Atp[4] = {At0, At0 + (long)AT_ELS, At0 + 2L * AT_ELS, A3t};

    for (int i = 0; i < 4; ++i) {
        long a_bs = (i == 3) ? (long)AT_ELS : 0;
        hop_fast<<<fgrid, blk, 0, stream>>>(Xt, XT_BS, KP, KP, Atp[i], a_bs, H1);
        hop_fast<<<fgrid, blk, 0, stream>>>(H1, H_BS, NN, NN, Atp[i], a_bs, H2);
        mix_kernel<<<mgrid, blk, 0, stream>>>(i == 0 ? x : nullptr, H1, H2, W, bias,
                                              2 * i + 1, 2 * i + 2, out, i == 0 ? 1 : 0);
    }
}